// Round 6
// baseline (703.808 us; speedup 1.0000x reference)
//
#include <hip/hip_runtime.h>

typedef unsigned short u16;
typedef unsigned int u32;
typedef __bf16 bf16x8 __attribute__((ext_vector_type(8)));
typedef float f32x4 __attribute__((ext_vector_type(4)));

#define BB   2
#define SS   2048
#define EE   2048
#define HH   2688
#define NHH  4
#define DHH  672
#define NPHH 672
#define H2   5376
#define H3   8064

__device__ __forceinline__ float b2f(u16 u) {
  union { unsigned int i; float f; } c; c.i = ((unsigned int)u) << 16; return c.f;
}
__device__ __forceinline__ u16 f2b(float f) {
  union { float f; unsigned int i; } c; c.f = f;
  unsigned int i = c.i;
  return (u16)((i + 0x7FFFu + ((i >> 16) & 1u)) >> 16);
}
__device__ __forceinline__ float silu_f(float x) { return x / (1.f + __expf(-x)); }
__device__ __forceinline__ float logsig_f(float f) {
  return (f >= 0.f) ? -log1pf(__expf(-f)) : (f - log1pf(__expf(f)));
}

// async global->LDS, 16B per lane; dst wave-uniform base, HW adds lane*16B
__device__ __forceinline__ void gl2lds16(const u16* g, u16* s) {
  __builtin_amdgcn_global_load_lds(
      (const __attribute__((address_space(1))) u32*)g,
      (__attribute__((address_space(3))) u32*)s, 16, 0, 0);
}

template <int N> __device__ __forceinline__ void vmwait() {
  asm volatile("s_waitcnt vmcnt(%0)" :: "n"(N) : "memory");
}

// ---------------------------------------------------------------------------
// gemm8: 2-phase NT GEMM (bf16), BK=64, 128x256 tile, 8 waves, ring-3 LDS,
// prefetch lead 2, vmcnt(6) per tile (never 0 mid-loop). Measured best
// per-makespan structure (r3: x@W_in 127us). XOR chunk swizzle both sides.
// MODE 0 plain; MODE 2 PV epilogue (row scale, causal K-cap). OUTF32: fp32.
// Requires: M % 128 == 0, K % 64 == 0. N masked on store; B staging may
// over-read up to 255 rows past N (callers guarantee in-bounds memory).
// ---------------------------------------------------------------------------
template <int MODE, int OUTF32>
__global__ __launch_bounds__(512, 1) void gemm8(
    const u16* __restrict__ A, const u16* __restrict__ Bt, void* __restrict__ Cp,
    int M, int N, int K, int lda, int ldb, int ldc,
    long sAhi, long sAlo, long sBhi, long sBlo, long sChi, long sClo,
    const float* __restrict__ aux1, const float* __restrict__ aux2,
    int auxStride, int causal)
{
  constexpr int SLOT = (128 + 256) * 64;   // u16 per ring slot (48 KiB)
  __shared__ __align__(16) u16 sm[3 * SLOT];  // 144 KiB

  int gx = gridDim.x;
  int nwg = gx * gridDim.y;
  int flat = blockIdx.y * gx + blockIdx.x;
  int qq = nwg >> 3, r8 = nwg & 7;
  int xcd = flat & 7, seq = flat >> 3;
  int logical = (xcd < r8 ? xcd * (qq + 1) : r8 * (qq + 1) + (xcd - r8) * qq) + seq;
  int bx = logical % gx, by = logical / gx;
  int m0 = by * 128, n0 = bx * 256;
  if (MODE == 1 && n0 > m0 + 127) return;

  int bz = blockIdx.z, bzh = bz >> 2, bzl = bz & 3;
  A  += bzh * sAhi + bzl * sAlo;
  Bt += bzh * sBhi + bzl * sBlo;
  const float* a1 = aux1 ? aux1 + (long)bz * auxStride : nullptr;
  const float* a2 = aux2 ? aux2 + (long)bz * auxStride : nullptr;
  u16*   C16 = (u16*)Cp + bzh * sChi + bzl * sClo;
  float* C32 = (float*)Cp + bzh * sChi + bzl * sClo;

  int t = threadIdx.x, lane = t & 63, w = t >> 6;
  int l15 = lane & 15, quad = lane >> 4;
  int wr = w >> 2, wc = w & 3;

  int srow = t >> 3;
  int sw8 = ((t & 7) ^ (srow & 7)) * 8;
  const u16* pS[6];
  int dOf[6];
#pragma unroll
  for (int c = 0; c < 2; ++c) {
    pS[c] = A + (long)(m0 + c * 64 + srow) * lda + sw8;
    dOf[c] = c * 4096 + w * 512;
  }
#pragma unroll
  for (int c = 0; c < 4; ++c) {
    pS[2 + c] = Bt + (long)(n0 + c * 64 + srow) * ldb + sw8;
    dOf[2 + c] = 8192 + c * 4096 + w * 512;
  }

  f32x4 acc[4][4];
#pragma unroll
  for (int i = 0; i < 4; i++)
#pragma unroll
    for (int j = 0; j < 4; j++) acc[i][j] = (f32x4){0.f, 0.f, 0.f, 0.f};

  int Keff = (MODE == 2 && causal) ? min(K, m0 + 128) : K;
  int T = Keff >> 6;

  auto STAGE = [&](int slot, int k2, int c) {
    gl2lds16(pS[c] + k2, sm + slot * SLOT + dOf[c]);
  };

  int npre = T < 2 ? T : 2;
  for (int tt = 0; tt < npre; ++tt)
#pragma unroll
    for (int c = 0; c < 6; ++c) STAGE(tt, tt << 6, c);
  if (npre >= 2) vmwait<6>(); else vmwait<0>();
  __builtin_amdgcn_s_barrier();
  __builtin_amdgcn_sched_barrier(0);

  int sl = 0;
  for (int tq = 0; tq < T; ++tq) {
    u16* Sb = sm + sl * SLOT;
    int sl2 = sl + 2; if (sl2 >= 3) sl2 -= 3;
    const bool stg = (tq + 2 < T);
    const int k2 = (tq + 2) << 6;
    int cx = (l15 & 7);

    bf16x8 bfr[4][2], af[2][2];
#pragma unroll
    for (int j = 0; j < 4; ++j)
#pragma unroll
      for (int ks = 0; ks < 2; ++ks)
        bfr[j][ks] = *reinterpret_cast<const bf16x8*>(
            Sb + 8192 + (wc * 64 + j * 16 + l15) * 64 + ((((ks << 2) + quad) ^ cx) << 3));
#pragma unroll
    for (int i = 0; i < 2; ++i)
#pragma unroll
      for (int ks = 0; ks < 2; ++ks)
        af[i][ks] = *reinterpret_cast<const bf16x8*>(
            Sb + (wr * 64 + i * 16 + l15) * 64 + ((((ks << 2) + quad) ^ cx) << 3));
    if (stg) { STAGE(sl2, k2, 0); STAGE(sl2, k2, 1); STAGE(sl2, k2, 2); }
    __builtin_amdgcn_s_barrier();
    asm volatile("s_waitcnt lgkmcnt(0)" ::: "memory");
    __builtin_amdgcn_sched_barrier(0);
    __builtin_amdgcn_s_setprio(1);
#pragma unroll
    for (int i = 0; i < 2; ++i)
#pragma unroll
      for (int j = 0; j < 4; ++j) {
        acc[i][j] = __builtin_amdgcn_mfma_f32_16x16x32_bf16(af[i][0], bfr[j][0], acc[i][j], 0, 0, 0);
        acc[i][j] = __builtin_amdgcn_mfma_f32_16x16x32_bf16(af[i][1], bfr[j][1], acc[i][j], 0, 0, 0);
      }
    __builtin_amdgcn_s_setprio(0);
    __builtin_amdgcn_sched_barrier(0);
    __builtin_amdgcn_s_barrier();

    bf16x8 ag[2][2];
#pragma unroll
    for (int i = 0; i < 2; ++i)
#pragma unroll
      for (int ks = 0; ks < 2; ++ks)
        ag[i][ks] = *reinterpret_cast<const bf16x8*>(
            Sb + (wr * 64 + (i + 2) * 16 + l15) * 64 + ((((ks << 2) + quad) ^ cx) << 3));
    if (stg) { STAGE(sl2, k2, 3); STAGE(sl2, k2, 4); STAGE(sl2, k2, 5); }
    __builtin_amdgcn_s_barrier();
    asm volatile("s_waitcnt lgkmcnt(0)" ::: "memory");
    __builtin_amdgcn_sched_barrier(0);
    __builtin_amdgcn_s_setprio(1);
#pragma unroll
    for (int i = 0; i < 2; ++i)
#pragma unroll
      for (int j = 0; j < 4; ++j) {
        acc[i + 2][j] = __builtin_amdgcn_mfma_f32_16x16x32_bf16(ag[i][0], bfr[j][0], acc[i + 2][j], 0, 0, 0);
        acc[i + 2][j] = __builtin_amdgcn_mfma_f32_16x16x32_bf16(ag[i][1], bfr[j][1], acc[i + 2][j], 0, 0, 0);
      }
    __builtin_amdgcn_s_setprio(0);
    __builtin_amdgcn_sched_barrier(0);
    if (tq + 1 < T) {
      if (stg) vmwait<6>(); else vmwait<0>();
      __builtin_amdgcn_s_barrier();
      __builtin_amdgcn_sched_barrier(0);
    }
    sl = sl + 1; if (sl >= 3) sl = 0;
  }

  const float rs = 0.03857583749f;  // 1/sqrt(672)
#pragma unroll
  for (int i = 0; i < 4; i++) {
#pragma unroll
    for (int j = 0; j < 4; j++) {
      int col = n0 + wc * 64 + j * 16 + l15;
      if (col >= N) continue;
#pragma unroll
      for (int rr = 0; rr < 4; rr++) {
        int row = m0 + wr * 64 + i * 16 + quad * 4 + rr;
        if (row >= M) continue;
        float v = acc[i][j][rr];
        if (MODE == 1) v = (col <= row) ? v * rs * __expf(a1[col] - a2[row]) : 0.f;
        else if (MODE == 2) v = v * a1[row];
        if (OUTF32) C32[(long)row * ldc + col] = v;
        else        C16[(long)row * ldc + col] = f2b(v);
      }
    }
  }
}

// ---------------------------------------------------------------------------
// Phase-interleaved NT GEMM (bf16), BK=32 — kept for QK (K=672 % 64 != 0).
// ---------------------------------------------------------------------------
template <int BM, int MODE, int OUTF32>
__global__ __launch_bounds__(512, 1) void gemm_p(
    const u16* __restrict__ A, const u16* __restrict__ Bt, void* __restrict__ Cp,
    int M, int N, int K, int lda, int ldb, int ldc,
    long sAhi, long sAlo, long sBhi, long sBlo, long sChi, long sClo,
    const float* __restrict__ aux1, const float* __restrict__ aux2,
    int auxStride, int causal)
{
  constexpr int MFR   = BM / 32;
  constexpr int NPH   = MFR / 2;
  constexpr int SLOT  = (BM + 256) * 32;
  constexpr int ACH   = BM / 128;
  constexpr int LOADS = ACH + 2;
  __shared__ __align__(16) u16 sm[4 * SLOT];

  int gx = gridDim.x;
  int nwg = gx * gridDim.y;
  int flat = blockIdx.y * gx + blockIdx.x;
  int qq = nwg >> 3, r8 = nwg & 7;
  int xcd = flat & 7, seq = flat >> 3;
  int logical = (xcd < r8 ? xcd * (qq + 1) : r8 * (qq + 1) + (xcd - r8) * qq) + seq;
  int bx = logical % gx, by = logical / gx;
  int m0 = by * BM, n0 = bx * 256;
  if (MODE == 1 && n0 > m0 + BM - 1) return;

  int bz = blockIdx.z, bzh = bz >> 2, bzl = bz & 3;
  A  += bzh * sAhi + bzl * sAlo;
  Bt += bzh * sBhi + bzl * sBlo;
  const float* a1 = aux1 ? aux1 + (long)bz * auxStride : nullptr;
  const float* a2 = aux2 ? aux2 + (long)bz * auxStride : nullptr;
  u16*   C16 = (u16*)Cp + bzh * sChi + bzl * sClo;
  float* C32 = (float*)Cp + bzh * sChi + bzl * sClo;

  int t = threadIdx.x, lane = t & 63, w = t >> 6;
  int l15 = lane & 15, quad = lane >> 4;
  int wr = w >> 2, wc = w & 3;

  int srow = t >> 2;
  int swz = (((t & 3) ^ ((t >> 3) & 3)) * 8);
  const u16* pS[LOADS];
  int coff[LOADS];
#pragma unroll
  for (int c = 0; c < ACH; ++c) {
    pS[c] = A + (long)(m0 + c * 128 + srow) * lda + swz;
    coff[c] = c * 4096 + w * 512;
  }
#pragma unroll
  for (int c = 0; c < 2; ++c) {
    pS[ACH + c] = Bt + (long)(n0 + c * 128 + srow) * ldb + swz;
    coff[ACH + c] = BM * 32 + c * 4096 + w * 512;
  }

  int rswz = (quad ^ ((l15 >> 1) & 3)) * 8;
  int aoff = (wr * (BM / 2) + l15) * 32 + rswz;
  int boff = BM * 32 + (wc * 64 + l15) * 32 + rswz;

  f32x4 acc[MFR][4];
#pragma unroll
  for (int i = 0; i < MFR; i++)
#pragma unroll
    for (int j = 0; j < 4; j++) acc[i][j] = (f32x4){0.f, 0.f, 0.f, 0.f};

  int Keff = (MODE == 2 && causal) ? min(K, m0 + BM) : K;
  int T = Keff >> 5;

  auto STAGE1 = [&](int tt, int c) {
    gl2lds16(pS[c] + (tt << 5), sm + (tt & 3) * SLOT + coff[c]);
  };

  int npre = T < 3 ? T : 3;
  for (int tt = 0; tt < npre; ++tt)
#pragma unroll
    for (int c = 0; c < LOADS; ++c) STAGE1(tt, c);
  if (npre >= 3)      vmwait<2 * LOADS>();
  else if (npre == 2) vmwait<LOADS>();
  else                vmwait<0>();
  __builtin_amdgcn_s_barrier();
  __builtin_amdgcn_sched_barrier(0);

  for (int tq = 0; tq < T; ++tq) {
    u16* Sb = sm + (tq & 3) * SLOT;
    const bool stg = (tq + 3 < T);
    bf16x8 bf[4];
#pragma unroll
    for (int p = 0; p < NPH; ++p) {
      bf16x8 a0 = *reinterpret_cast<const bf16x8*>(Sb + aoff + (2 * p) * 512);
      bf16x8 a1v = *reinterpret_cast<const bf16x8*>(Sb + aoff + (2 * p + 1) * 512);
      if (p == 0) {
#pragma unroll
        for (int j = 0; j < 4; ++j)
          bf[j] = *reinterpret_cast<const bf16x8*>(Sb + boff + j * 512);
      }
      if (stg) {
#pragma unroll
        for (int c = p * LOADS / NPH; c < (p + 1) * LOADS / NPH; ++c)
          STAGE1(tq + 3, c);
      }
      __builtin_amdgcn_s_barrier();
      asm volatile("s_waitcnt lgkmcnt(0)" ::: "memory");
      __builtin_amdgcn_sched_barrier(0);
      __builtin_amdgcn_s_setprio(1);
#pragma unroll
      for (int j = 0; j < 4; ++j)
        acc[2 * p][j] = __builtin_amdgcn_mfma_f32_16x16x32_bf16(a0, bf[j], acc[2 * p][j], 0, 0, 0);
#pragma unroll
      for (int j = 0; j < 4; ++j)
        acc[2 * p + 1][j] = __builtin_amdgcn_mfma_f32_16x16x32_bf16(a1v, bf[j], acc[2 * p + 1][j], 0, 0, 0);
      __builtin_amdgcn_s_setprio(0);
      __builtin_amdgcn_sched_barrier(0);
    }
    if (tq + 1 < T) {
      if (tq + 3 < T)      vmwait<2 * LOADS>();
      else if (tq + 2 < T) vmwait<LOADS>();
      else                 vmwait<0>();
      __builtin_amdgcn_s_barrier();
      __builtin_amdgcn_sched_barrier(0);
    }
  }

  const float rs = 0.03857583749f;  // 1/sqrt(672)
#pragma unroll
  for (int i = 0; i < MFR; i++) {
#pragma unroll
    for (int j = 0; j < 4; j++) {
      int col = n0 + wc * 64 + j * 16 + l15;
      if (col >= N) continue;
#pragma unroll
      for (int rr = 0; rr < 4; rr++) {
        int row = m0 + wr * (BM / 2) + i * 16 + quad * 4 + rr;
        if (row >= M) continue;
        float v = acc[i][j][rr];
        if (MODE == 1) v = (col <= row) ? v * rs * __expf(a1[col] - a2[row]) : 0.f;
        else if (MODE == 2) v = v * a1[row];
        if (OUTF32) C32[(long)row * ldc + col] = v;
        else        C16[(long)row * ldc + col] = f2b(v);
      }
    }
  }
}

// ---------------------------------------------------------------------------
// transpose with row stride: out[c*R + r] = in[r*ldin + c]; F32IN: fp32 source
// ---------------------------------------------------------------------------
template <int F32IN>
__global__ __launch_bounds__(256) void transpose_any(
    const void* __restrict__ in, u16* __restrict__ out, int R, int C, int ldin,
    long inHi, long inLo, long outStride)
{
  __shared__ u16 tile[64][65];
  int bz = blockIdx.z, bzh = bz >> 2, bzl = bz & 3;
  const u16* in16 = (const u16*)in + bzh * inHi + bzl * inLo;
  const float* inf = (const float*)in + bzh * inHi + bzl * inLo;
  out += (long)bz * outStride;
  int r0 = blockIdx.y * 64, c0 = blockIdx.x * 64;
  int t = threadIdx.x;
  for (int idx = t; idx < 64 * 64; idx += 256) {
    int r = idx >> 6, c = idx & 63;
    int rr = r0 + r, cc = c0 + c;
    u16 v = 0;
    if (rr < R && cc < C) {
      long off = (long)rr * ldin + cc;
      v = F32IN ? f2b(inf[off]) : in16[off];
    }
    tile[r][c] = v;
  }
  __syncthreads();
  for (int idx = t; idx < 64 * 64; idx += 256) {
    int r = idx & 63, c = idx >> 6;
    int rr = r0 + r, cc = c0 + c;
    if (rr < R && cc < C) out[(long)cc * R + rr] = tile[r][c];
  }
}

// ---------------------------------------------------------------------------
// x fp32 -> bf16, 8/thread
__global__ __launch_bounds__(256) void convert_x(
    const float* __restrict__ x, u16* __restrict__ o)
{
  long i = ((long)blockIdx.x * 256 + threadIdx.x) * 8;
  if (i >= (long)4096 * EE) return;
  float4 a = *reinterpret_cast<const float4*>(x + i);
  float4 b = *reinterpret_cast<const float4*>(x + i + 4);
  u16 t8[8] = {f2b(a.x), f2b(a.y), f2b(a.z), f2b(a.w),
               f2b(b.x), f2b(b.y), f2b(b.z), f2b(b.w)};
  *reinterpret_cast<uint4*>(o + i) = *reinterpret_cast<uint4*>(t8);
}

// ---------------------------------------------------------------------------
// Wq|Wk|Wv fp32 -> bf16 packed (3 x 10752)
__global__ __launch_bounds__(256) void prep_wqkv(
    const float* __restrict__ Wq, const float* __restrict__ Wk,
    const float* __restrict__ Wv, u16* __restrict__ o)
{
  int i = blockIdx.x * 256 + threadIdx.x;
  if (i >= 3 * 10752) return;
  int m = i / 10752, j = i % 10752;
  const float* W = (m == 0) ? Wq : (m == 1) ? Wk : Wv;
  o[i] = f2b(W[j]);
}

// ---------------------------------------------------------------------------
// Gate weights packed per-nph: Wg[nph*96 + seg*32 + d*8 + j] (bf16)
//   j<4 -> W_ig[(seg*2688 + nph*4 + d)*4 + j]; j>=4 -> W_fg[...][j-4]
// so each conv_head thread reads 12 contiguous uint4 (192 B).
// ---------------------------------------------------------------------------
__global__ __launch_bounds__(256) void prep_gatew(
    const float* __restrict__ Wig, const float* __restrict__ Wfg,
    u16* __restrict__ Wg)
{
  int i = blockIdx.x * 256 + threadIdx.x;
  if (i >= NPHH * 96) return;
  int nph = i / 96, r = i % 96;
  int seg = r >> 5, d = (r >> 3) & 3, j = r & 7;
  const float* W = (j < 4) ? Wig : Wfg;
  Wg[i] = f2b(W[(long)(seg * HH + nph * 4 + d) * 4 + (j & 3)]);
}

// ---------------------------------------------------------------------------
// FUSED: depthwise causal conv (KS=4) + bias + silu + headwise 4x4 q/k/v
// + gate pre-activation reduction. One block per (b,s); threads 0..671 own
// one nph each (704 launched; tail lanes contribute zeros). Per-thread gate
// partials (96 FMA vs prepacked Wg) are wave shuffle-reduced, LDS-atomic
// combined, and written compactly to G2[bs*8 + {0..3 ig, 4..7 fg}].
// Replaces gate_gemv (VALU-bound ~50us) and its 66 MB q/k/v re-read.
// ---------------------------------------------------------------------------
__global__ __launch_bounds__(704) void conv_head(
    const u16* __restrict__ xinner, const float* __restrict__ cw,
    const float* __restrict__ cb, const u16* __restrict__ Wqkv,
    const u16* __restrict__ Wg, u16* __restrict__ xca, u16* __restrict__ q,
    u16* __restrict__ k, u16* __restrict__ v, float* __restrict__ G2)
{
  __shared__ float gsh[8];
  long bs = blockIdx.x;
  int s = (int)(bs % SS);
  int t = threadIdx.x, lane = t & 63;
  if (t < 8) gsh[t] = 0.f;
  __syncthreads();

  float gi[4] = {0.f, 0.f, 0.f, 0.f}, gf[4] = {0.f, 0.f, 0.f, 0.f};
  if (t < NPHH) {
    int h4 = t * 4;
    float4 acc = *reinterpret_cast<const float4*>(cb + h4);
    uint2 xmr = {0, 0};  // tap w=3 = x_m row bs (always in-bounds)
#pragma unroll
    for (int w = 0; w < 4; w++) {
      int sp = s + w - 3;
      if (sp < 0) continue;
      uint2 xr = *reinterpret_cast<const uint2*>(xinner + (bs + w - 3) * H2 + h4);
      if (w == 3) xmr = xr;
      const u16* xh = (const u16*)&xr;
      float4 cwv = *reinterpret_cast<const float4*>(cw + w * HH + h4);
      acc.x += b2f(xh[0]) * cwv.x;
      acc.y += b2f(xh[1]) * cwv.y;
      acc.z += b2f(xh[2]) * cwv.z;
      acc.w += b2f(xh[3]) * cwv.w;
    }
    float xaf[4] = {silu_f(acc.x), silu_f(acc.y), silu_f(acc.z), silu_f(acc.w)};
    u16 xa16[4] = {f2b(xaf[0]), f2b(xaf[1]), f2b(xaf[2]), f2b(xaf[3])};
#pragma unroll
    for (int d = 0; d < 4; d++) xaf[d] = b2f(xa16[d]);
    const u16* xm = (const u16*)&xmr;
    float xmf[4];
#pragma unroll
    for (int d = 0; d < 4; d++) xmf[d] = b2f(xm[d]);
    *reinterpret_cast<uint2*>(xca + bs * HH + h4) = *reinterpret_cast<uint2*>(xa16);

    union { uint4 v4[2]; u16 h[16]; } wq, wk, wv;
    const uint4* wqp = reinterpret_cast<const uint4*>(Wqkv + t * 16);
    const uint4* wkp = reinterpret_cast<const uint4*>(Wqkv + 10752 + t * 16);
    const uint4* wvp = reinterpret_cast<const uint4*>(Wqkv + 21504 + t * 16);
    wq.v4[0] = wqp[0]; wq.v4[1] = wqp[1];
    wk.v4[0] = wkp[0]; wk.v4[1] = wkp[1];
    wv.v4[0] = wvp[0]; wv.v4[1] = wvp[1];
    float aq[4], ak[4], av[4];
    u16 qo[4], ko[4], vo[4];
#pragma unroll
    for (int o = 0; o < 4; o++) {
      float sq = 0.f, sk = 0.f, sv = 0.f;
#pragma unroll
      for (int d = 0; d < 4; d++) {
        sq += xaf[d] * b2f(wq.h[d * 4 + o]);
        sk += xaf[d] * b2f(wk.h[d * 4 + o]);
        sv += xmf[d] * b2f(wv.h[d * 4 + o]);
      }
      aq[o] = sq; ak[o] = sk; av[o] = sv;
      qo[o] = f2b(sq); ko[o] = f2b(sk); vo[o] = f2b(sv);
    }
    long ob = bs * HH + h4;
    *reinterpret_cast<uint2*>(q + ob) = *reinterpret_cast<uint2*>(qo);
    *reinterpret_cast<uint2*>(k + ob) = *reinterpret_cast<uint2*>(ko);
    *reinterpret_cast<uint2*>(v + ob) = *reinterpret_cast<uint2*>(vo);

    // gate partials: 96 bf16 weights, contiguous per nph
    union { uint4 v4[12]; u16 h[96]; } wg;
    const uint4* wgp = reinterpret_cast<const uint4*>(Wg + t * 96);
#pragma unroll
    for (int u = 0; u < 12; ++u) wg.v4[u] = wgp[u];
#pragma unroll
    for (int seg = 0; seg < 3; ++seg) {
      const float* xx = (seg == 0) ? aq : (seg == 1) ? ak : av;
#pragma unroll
      for (int d = 0; d < 4; ++d) {
        float xv = xx[d];
        const u16* wr = &wg.h[seg * 32 + d * 8];
#pragma unroll
        for (int n = 0; n < 4; ++n) {
          gi[n] += xv * b2f(wr[n]);
          gf[n] += xv * b2f(wr[4 + n]);
        }
      }
    }
  }
  // wave reduce 8 partials, then LDS-atomic combine across waves
#pragma unroll
  for (int off = 32; off > 0; off >>= 1) {
#pragma unroll
    for (int n = 0; n < 4; ++n) {
      gi[n] += __shfl_down(gi[n], off);
      gf[n] += __shfl_down(gf[n], off);
    }
  }
  if (lane == 0) {
#pragma unroll
    for (int n = 0; n < 4; ++n) {
      atomicAdd(&gsh[n], gi[n]);
      atomicAdd(&gsh[4 + n], gf[n]);
    }
  }
  __syncthreads();
  if (t < 8) G2[bs * 8 + t] = gsh[t];
}

// ---------------------------------------------------------------------------
// scan: per (b,n): ip/fp from compact G2 + bias; cs = cumsum(logsig(fp));
// a = ip - cs; rmax = prefix-max(a); m = cs + rmax.
// 256 threads x 8 serial elems; wave shfl_up scans + 4-wave LDS combine
// (2 barriers total vs the old 22 Hillis-Steele passes).
// ---------------------------------------------------------------------------
__global__ __launch_bounds__(256) void scan_kernel(
    const float* __restrict__ G2, const float* __restrict__ big,
    const float* __restrict__ bfg,
    float* __restrict__ avec, float* __restrict__ rmaxvec, float* __restrict__ mvec)
{
  __shared__ float wsum[4], wmax[4];
  int bn = blockIdx.x;
  int b = bn >> 2, n = bn & 3;
  int t = threadIdx.x, lane = t & 63, wv = t >> 6;
  float bi = big[n], bf = bfg[n];
  int i0 = t * 8;
  float ip[8], ls[8];
  float run = 0.f;
#pragma unroll
  for (int kk = 0; kk < 8; ++kk) {
    long tk = (long)b * SS + i0 + kk;
    ip[kk] = G2[tk * 8 + n] + bi;
    run += logsig_f(G2[tk * 8 + 4 + n] + bf);
    ls[kk] = run;
  }
  // inclusive sum-scan of per-thread totals across the wave
  float v = run;
#pragma unroll
  for (int off = 1; off < 64; off <<= 1) {
    float o = __shfl_up(v, off);
    if (lane >= off) v += o;
  }
  if (lane == 63) wsum[wv] = v;
  __syncthreads();
  float woff = 0.f;
  for (int u = 0; u < wv; ++u) woff += wsum[u];
  float excl = v - run + woff;   // exclusive prefix for this thread's chunk
  float a[8], lm[8];
  float runm = -3.4e38f;
#pragma unroll
  for (int kk = 0; kk < 8; ++kk) {
    float cs = excl + ls[kk];
    ls[kk] = cs;
    a[kk] = ip[kk] - cs;
    runm = fmaxf(runm, a[kk]);
    lm[kk] = runm;
    avec[(long)bn * SS + i0 + kk] = a[kk];
  }
  // inclusive max-scan of per-thread maxima across the wave
  float mv = runm;
#pragma unroll
  for (int off = 1; off < 64; off <<= 1) {
    float o = __shfl_up(mv, off);
    if (lane >= off) mv = fmaxf(mv, o);
  }
  if (lane == 63) wmax[wv] = mv;
  __syncthreads();
  float woffm = -3.4e38f;
  for (int u = 0; u < wv; ++u) woffm = fmaxf(woffm, wmax[u]);
  float pm = __shfl_up(mv, 1);
  float pre = (lane == 0) ? woffm : fmaxf(woffm, pm);
#pragma unroll
  for (int kk = 0; kk < 8; ++kk) {
    float r = fmaxf(pre, lm[kk]);
    rmaxvec[(long)bn * SS + i0 + kk] = r;
    mvec[(long)bn * SS + i0 + kk] = ls[kk] + r;
  }
}

// ---------------------------------------------------------------------------
// causal row sums of P -> inv_n (vectorized uint4 + in-bounds scalar tail)
__global__ __launch_bounds__(256) void rowsum_kernel(
    const u16* __restrict__ P, const float* __restrict__ mvec, float* __restrict__ invn,
    long Pstride)
{
  int bz = blockIdx.z;
  P += (long)bz * Pstride;
  mvec += (long)bz * SS;
  invn += (long)bz * SS;
  int row = (blockIdx.x * 256 + threadIdx.x) >> 6;
  int lane = threadIdx.x & 63;
  if (row >= SS) return;
  const u16* pr = P + (long)row * SS;
  float s = 0.f;
  int j0 = lane * 8;
  for (; j0 + 7 <= row; j0 += 512) {
    uint4 u = *reinterpret_cast<const uint4*>(pr + j0);
    const u16* e = (const u16*)&u;
#pragma unroll
    for (int q = 0; q < 8; ++q) s += b2f(e[q]);
  }
  if (j0 <= row) {
    for (int q = 0; j0 + q <= row; ++q) s += b2f(pr[j0 + q]);
  }
#pragma unroll
  for (int off = 32; off > 0; off >>= 1) s += __shfl_down(s, off);
  if (lane == 0) {
    float n = fmaxf(fabsf(s), __expf(-mvec[row]));
    invn[row] = 1.f / (n + 1e-6f);
  }
}

// ---------------------------------------------------------------------------
// multi-head layernorm + skip + gate (paired u32 bf16 loads)
__global__ __launch_bounds__(256) void ln_skip_gate(
    const u16* __restrict__ h, const u16* __restrict__ xca,
    const u16* __restrict__ xinner, const float* __restrict__ normw,
    const float* __restrict__ skipw, u16* __restrict__ hs)
{
  int row = (blockIdx.x * 256 + threadIdx.x) >> 6;  // (b*NH+n)*S + s
  int lane = threadIdx.x & 63;
  if (row >= BB * NHH * SS) return;
  int s = row % SS;
  int n = (row / SS) % NHH;
  int b = row / (SS * NHH);
  const u16* hr = h + (long)row * DHH;
  float sum = 0.f, ss = 0.f;
  float vx[6], vy[6];
#pragma unroll
  for (int i = 0; i < 6; ++i) {
    int d2 = lane + i * 64;
    float x = 0.f, y = 0.f;
    if (d2 < DHH / 2) {
      u32 u = *reinterpret_cast<const u32*>(hr + d2 * 2);
      x = b2f((u16)u); y = b2f((u16)(u >> 16));
    }
    vx[i] = x; vy[i] = y;
    sum += x + y; ss += x * x + y * y;
  }
#pragma unroll
  for (int off = 32; off > 0; off >>= 1) { sum += __shfl_down(sum, off); ss += __shfl_down(ss, off); }
  sum = __shfl(sum, 0); ss = __shfl(ss, 0);
  float mu = sum / (float)DHH;
  float var = ss / (float)DHH - mu * mu;
  float rstd = rsqrtf(var + 1e-5f);
  long bs = (long)b * SS + s;
#pragma unroll
  for (int i = 0; i < 6; ++i) {
    int d2 = lane + i * 64;
    if (d2 >= DHH / 2) continue;
    int c = n * DHH + d2 * 2;
    float2 nw = *reinterpret_cast<const float2*>(normw + c);
    float2 sw = *reinterpret_cast<const float2*>(skipw + c);
    u32 xcu = *reinterpret_cast<const u32*>(xca + bs * HH + c);
    u32 zu  = *reinterpret_cast<const u32*>(xinner + bs * H2 + HH + c);
    float h0 = (vx[i] - mu) * rstd * nw.x + sw.x * b2f((u16)xcu);
    float h1 = (vy[i] - mu) * rstd * nw.y + sw.y * b2f((u16)(xcu >> 16));
    float o0 = h0 * silu_f(b2f((u16)zu));
    float o1 = h1 * silu_f(b2f((u16)(zu >> 16)));
    u32 ou = (u32)f2b(o0) | ((u32)f2b(o1) << 16);
    *reinterpret_cast<u32*>(hs + bs * HH + c) = ou;
  }
}

// ---------------------------------------------------------------------------
__global__ __launch_bounds__(256) void fill_sentinel(float* out, float v, long n) {
  long i = (long)blockIdx.x * 256 + threadIdx.x;
  if (i < n) out[i] = v;
}

// ---------------------------------------------------------------------------
extern "C" void kernel_launch(void* const* d_in, const int* in_sizes, int n_in,
                              void* d_out, int out_size, void* d_ws, size_t ws_size,
                              hipStream_t stream)
{
  const float* x      = (const float*)d_in[0];
  const float* W_in   = (const float*)d_in[1];
  const float* conv_w = (const float*)d_in[2];
  const float* conv_b = (const float*)d_in[3];
  const float* Wq     = (const float*)d_in[4];
  const float* Wk     = (const float*)d_in[5];
  const float* Wv     = (const float*)d_in[6];
  const float* W_ig   = (const float*)d_in[7];
  const float* b_ig   = (const float*)d_in[8];
  const float* W_fg   = (const float*)d_in[9];
  const float* b_fg   = (const float*)d_in[10];
  const float* norm_w = (const float*)d_in[11];
  const float* skipw  = (const float*)d_in[12];
  const float* W_out  = (const float*)d_in[13];
  float* out = (float*)d_out;
  const long SD = (long)SS * DHH;     // head slice elems
  const long SP = (long)SS * SS;
  const long BH = (long)SS * HH;      // per-batch elems of (S,H)

  u16* ws = (u16*)d_ws;
  size_t off = 0;
  auto alloc = [&](size_t n) { u16* p = ws + off; off += n; return p; };
  u16* x_inner = alloc((size_t)4096 * H2);
  u16* xca     = alloc((size_t)4096 * HH);
  u16* qb      = alloc((size_t)4096 * HH);   // W_inT -> q -> hs
  u16* kb      = alloc((size_t)4096 * HH);   // xbf -> k -> h
  u16* vb      = alloc((size_t)4096 * HH);   // v -> W_outT
  float* fvec  = (float*)(ws + off);
  off += 4 * 16384 * 2;
  float* avec    = fvec;
  float* rmaxvec = avec + 16384;
  float* mvec    = rmaxvec + 16384;
  float* invn    = mvec + 16384;
  u16* vt8 = alloc((size_t)8 * SD);
  u16* Pb8 = alloc((size_t)8 * SP);
  size_t need = off * 2;
  long outn = (long)4096 * EE;

  if (ws_size < need) {
    fill_sentinel<<<dim3((outn + 255) / 256), 256, 0, stream>>>(
        out, 200.f + 0.01f * (float)(ws_size >> 20), outn);
    return;
  }

  // overlays
  u16* W_inT  = qb;                       // consumed before conv_head writes q
  u16* xbf    = kb;                       // consumed before conv_head writes k
  u16* W_outT = vb;                       // written after v's last use
  u16* hbuf   = kb;                       // h (bn,S,DH) after k's last use
  u16* hsbuf  = qb;                       // hs after q's last use
  float* G2   = (float*)(Pb8 + 344064);   // 4096 x 8 fp32, consumed before QK
  u16* Wqkv   = Pb8 + 933888;             // 3x10752, consumed before QK
  u16* Wg     = Pb8 + 966144;             // 672x96 bf16 gate weights

  prep_wqkv<<<dim3(126, 1, 1), 256, 0, stream>>>(Wq, Wk, Wv, Wqkv);
  prep_gatew<<<dim3(252, 1, 1), 256, 0, stream>>>(W_ig, W_fg, Wg);
  fill_sentinel<<<dim3(128, 1, 1), 256, 0, stream>>>(G2, 0.f, 32768);
  transpose_any<1><<<dim3(84, 32, 1), 256, 0, stream>>>(
      W_in, W_inT, EE, H2, H2, 0, 0, 0);
  convert_x<<<dim3(4096, 1, 1), 256, 0, stream>>>(x, xbf);
  // x_inner = x @ W_in : M=4096 N=5376 K=2048 (128x256 tiles, 672 blocks)
  gemm8<0, 0><<<dim3(21, 32, 1), 512, 0, stream>>>(
      xbf, W_inT, x_inner, 4096, H2, EE, EE, EE, H2,
      0, 0, 0, 0, 0, 0, nullptr, nullptr, 0, 0);
  // fused conv+silu+headwise+gates: writes xca, q, k, v, G2
  conv_head<<<dim3(4096, 1, 1), 704, 0, stream>>>(
      x_inner, conv_w, conv_b, Wqkv, Wg, xca, qb, kb, vb, G2);
  scan_kernel<<<dim3(8, 1, 1), 256, 0, stream>>>(G2, b_ig, b_fg, avec, rmaxvec, mvec);
  // v^T per (b,n): (DH, S)
  transpose_any<0><<<dim3(11, 32, 8), 256, 0, stream>>>(
      vb, vt8, SS, DHH, HH, BH, DHH, SD);
  // P = (q k^T / sqrt(DH)) * exp(a[col]-rmax[row]), causal; K=672 -> BK32 path
  gemm_p<256, 1, 0><<<dim3(8, 8, 8), 512, 0, stream>>>(
      qb, kb, Pb8, SS, SS, DHH, HH, HH, SS,
      BH, DHH, BH, DHH, 4 * SP, SP, avec, rmaxvec, SS, 0);
  rowsum_kernel<<<dim3(512, 1, 8), 256, 0, stream>>>(Pb8, mvec, invn, SP);
  // h = (P @ v) * inv_n, into (bn, S, DH); Keff = m0+128 (mult of 64 ok);
  // B over-reads vt8 rows 672..767 (in-bounds garbage, masked by col<N)
  gemm8<2, 0><<<dim3(3, 16, 8), 512, 0, stream>>>(
      Pb8, vt8, hbuf, SS, DHH, SS, SS, SS, DHH,
      4 * SP, SP, 4 * SD, SD, 4 * SD, SD, invn, nullptr, SS, 1);
  transpose_any<1><<<dim3(32, 42, 1), 256, 0, stream>>>(
      W_out, W_outT, HH, EE, EE, 0, 0, 0);
  ln_skip_gate<<<dim3(4096, 1, 1), 256, 0, stream>>>(
      hbuf, xca, x_inner, norm_w, skipw, hsbuf);
  gemm8<0, 1><<<dim3(8, 32, 1), 512, 0, stream>>>(
      hsbuf, W_outT, out, 4096, EE, HH, HH, HH, EE,
      0, 0, 0, 0, 0, 0, nullptr, nullptr, 0, 0);
}

// Round 7
// 651.966 us; speedup vs baseline: 1.0795x; 1.0795x over previous
//
#include <hip/hip_runtime.h>

typedef unsigned short u16;
typedef unsigned int u32;
typedef __bf16 bf16x8 __attribute__((ext_vector_type(8)));
typedef float f32x4 __attribute__((ext_vector_type(4)));

#define BB   2
#define SS   2048
#define EE   2048
#define HH   2688
#define NHH  4
#define DHH  672
#define NPHH 672
#define H2   5376
#define H3   8064

__device__ __forceinline__ float b2f(u16 u) {
  union { unsigned int i; float f; } c; c.i = ((unsigned int)u) << 16; return c.f;
}
__device__ __forceinline__ u16 f2b(float f) {
  union { float f; unsigned int i; } c; c.f = f;
  unsigned int i = c.i;
  return (u16)((i + 0x7FFFu + ((i >> 16) & 1u)) >> 16);
}
__device__ __forceinline__ float silu_f(float x) { return x / (1.f + __expf(-x)); }
__device__ __forceinline__ float logsig_f(float f) {
  return (f >= 0.f) ? -log1pf(__expf(-f)) : (f - log1pf(__expf(f)));
}

// async global->LDS, 16B per lane; dst wave-uniform base, HW adds lane*16B
__device__ __forceinline__ void gl2lds16(const u16* g, u16* s) {
  __builtin_amdgcn_global_load_lds(
      (const __attribute__((address_space(1))) u32*)g,
      (__attribute__((address_space(3))) u32*)s, 16, 0, 0);
}

template <int N> __device__ __forceinline__ void vmwait() {
  asm volatile("s_waitcnt vmcnt(%0)" :: "n"(N) : "memory");
}

// ---------------------------------------------------------------------------
// gemm8: 2-phase NT GEMM (bf16), BK=64, 128x256 tile, 8 waves, ring-3 LDS,
// prefetch lead 2, vmcnt(6) per tile (never 0 mid-loop). Measured best
// per-makespan structure (r3: x@W_in 127us). XOR chunk swizzle both sides.
// MODE 0 plain; MODE 2 PV epilogue (row scale, causal K-cap). OUTF32: fp32.
// Requires: M % 128 == 0, K % 64 == 0. N masked on store; B staging may
// over-read up to 255 rows past N (callers guarantee in-bounds memory).
// ---------------------------------------------------------------------------
template <int MODE, int OUTF32>
__global__ __launch_bounds__(512, 1) void gemm8(
    const u16* __restrict__ A, const u16* __restrict__ Bt, void* __restrict__ Cp,
    int M, int N, int K, int lda, int ldb, int ldc,
    long sAhi, long sAlo, long sBhi, long sBlo, long sChi, long sClo,
    const float* __restrict__ aux1, const float* __restrict__ aux2,
    int auxStride, int causal)
{
  constexpr int SLOT = (128 + 256) * 64;   // u16 per ring slot (48 KiB)
  __shared__ __align__(16) u16 sm[3 * SLOT];  // 144 KiB

  int gx = gridDim.x;
  int nwg = gx * gridDim.y;
  int flat = blockIdx.y * gx + blockIdx.x;
  int qq = nwg >> 3, r8 = nwg & 7;
  int xcd = flat & 7, seq = flat >> 3;
  int logical = (xcd < r8 ? xcd * (qq + 1) : r8 * (qq + 1) + (xcd - r8) * qq) + seq;
  int bx = logical % gx, by = logical / gx;
  int m0 = by * 128, n0 = bx * 256;
  if (MODE == 1 && n0 > m0 + 127) return;

  int bz = blockIdx.z, bzh = bz >> 2, bzl = bz & 3;
  A  += bzh * sAhi + bzl * sAlo;
  Bt += bzh * sBhi + bzl * sBlo;
  const float* a1 = aux1 ? aux1 + (long)bz * auxStride : nullptr;
  const float* a2 = aux2 ? aux2 + (long)bz * auxStride : nullptr;
  u16*   C16 = (u16*)Cp + bzh * sChi + bzl * sClo;
  float* C32 = (float*)Cp + bzh * sChi + bzl * sClo;

  int t = threadIdx.x, lane = t & 63, w = t >> 6;
  int l15 = lane & 15, quad = lane >> 4;
  int wr = w >> 2, wc = w & 3;

  int srow = t >> 3;
  int sw8 = ((t & 7) ^ (srow & 7)) * 8;
  const u16* pS[6];
  int dOf[6];
#pragma unroll
  for (int c = 0; c < 2; ++c) {
    pS[c] = A + (long)(m0 + c * 64 + srow) * lda + sw8;
    dOf[c] = c * 4096 + w * 512;
  }
#pragma unroll
  for (int c = 0; c < 4; ++c) {
    pS[2 + c] = Bt + (long)(n0 + c * 64 + srow) * ldb + sw8;
    dOf[2 + c] = 8192 + c * 4096 + w * 512;
  }

  f32x4 acc[4][4];
#pragma unroll
  for (int i = 0; i < 4; i++)
#pragma unroll
    for (int j = 0; j < 4; j++) acc[i][j] = (f32x4){0.f, 0.f, 0.f, 0.f};

  int Keff = (MODE == 2 && causal) ? min(K, m0 + 128) : K;
  int T = Keff >> 6;

  auto STAGE = [&](int slot, int k2, int c) {
    gl2lds16(pS[c] + k2, sm + slot * SLOT + dOf[c]);
  };

  int npre = T < 2 ? T : 2;
  for (int tt = 0; tt < npre; ++tt)
#pragma unroll
    for (int c = 0; c < 6; ++c) STAGE(tt, tt << 6, c);
  if (npre >= 2) vmwait<6>(); else vmwait<0>();
  __builtin_amdgcn_s_barrier();
  __builtin_amdgcn_sched_barrier(0);

  int sl = 0;
  for (int tq = 0; tq < T; ++tq) {
    u16* Sb = sm + sl * SLOT;
    int sl2 = sl + 2; if (sl2 >= 3) sl2 -= 3;
    const bool stg = (tq + 2 < T);
    const int k2 = (tq + 2) << 6;
    int cx = (l15 & 7);

    bf16x8 bfr[4][2], af[2][2];
#pragma unroll
    for (int j = 0; j < 4; ++j)
#pragma unroll
      for (int ks = 0; ks < 2; ++ks)
        bfr[j][ks] = *reinterpret_cast<const bf16x8*>(
            Sb + 8192 + (wc * 64 + j * 16 + l15) * 64 + ((((ks << 2) + quad) ^ cx) << 3));
#pragma unroll
    for (int i = 0; i < 2; ++i)
#pragma unroll
      for (int ks = 0; ks < 2; ++ks)
        af[i][ks] = *reinterpret_cast<const bf16x8*>(
            Sb + (wr * 64 + i * 16 + l15) * 64 + ((((ks << 2) + quad) ^ cx) << 3));
    if (stg) { STAGE(sl2, k2, 0); STAGE(sl2, k2, 1); STAGE(sl2, k2, 2); }
    __builtin_amdgcn_s_barrier();
    asm volatile("s_waitcnt lgkmcnt(0)" ::: "memory");
    __builtin_amdgcn_sched_barrier(0);
    __builtin_amdgcn_s_setprio(1);
#pragma unroll
    for (int i = 0; i < 2; ++i)
#pragma unroll
      for (int j = 0; j < 4; ++j) {
        acc[i][j] = __builtin_amdgcn_mfma_f32_16x16x32_bf16(af[i][0], bfr[j][0], acc[i][j], 0, 0, 0);
        acc[i][j] = __builtin_amdgcn_mfma_f32_16x16x32_bf16(af[i][1], bfr[j][1], acc[i][j], 0, 0, 0);
      }
    __builtin_amdgcn_s_setprio(0);
    __builtin_amdgcn_sched_barrier(0);
    __builtin_amdgcn_s_barrier();

    bf16x8 ag[2][2];
#pragma unroll
    for (int i = 0; i < 2; ++i)
#pragma unroll
      for (int ks = 0; ks < 2; ++ks)
        ag[i][ks] = *reinterpret_cast<const bf16x8*>(
            Sb + (wr * 64 + (i + 2) * 16 + l15) * 64 + ((((ks << 2) + quad) ^ cx) << 3));
    if (stg) { STAGE(sl2, k2, 3); STAGE(sl2, k2, 4); STAGE(sl2, k2, 5); }
    __builtin_amdgcn_s_barrier();
    asm volatile("s_waitcnt lgkmcnt(0)" ::: "memory");
    __builtin_amdgcn_sched_barrier(0);
    __builtin_amdgcn_s_setprio(1);
#pragma unroll
    for (int i = 0; i < 2; ++i)
#pragma unroll
      for (int j = 0; j < 4; ++j) {
        acc[i + 2][j] = __builtin_amdgcn_mfma_f32_16x16x32_bf16(ag[i][0], bfr[j][0], acc[i + 2][j], 0, 0, 0);
        acc[i + 2][j] = __builtin_amdgcn_mfma_f32_16x16x32_bf16(ag[i][1], bfr[j][1], acc[i + 2][j], 0, 0, 0);
      }
    __builtin_amdgcn_s_setprio(0);
    __builtin_amdgcn_sched_barrier(0);
    if (tq + 1 < T) {
      if (stg) vmwait<6>(); else vmwait<0>();
      __builtin_amdgcn_s_barrier();
      __builtin_amdgcn_sched_barrier(0);
    }
    sl = sl + 1; if (sl >= 3) sl = 0;
  }

  const float rs = 0.03857583749f;  // 1/sqrt(672)
#pragma unroll
  for (int i = 0; i < 4; i++) {
#pragma unroll
    for (int j = 0; j < 4; j++) {
      int col = n0 + wc * 64 + j * 16 + l15;
      if (col >= N) continue;
#pragma unroll
      for (int rr = 0; rr < 4; rr++) {
        int row = m0 + wr * 64 + i * 16 + quad * 4 + rr;
        if (row >= M) continue;
        float v = acc[i][j][rr];
        if (MODE == 1) v = (col <= row) ? v * rs * __expf(a1[col] - a2[row]) : 0.f;
        else if (MODE == 2) v = v * a1[row];
        if (OUTF32) C32[(long)row * ldc + col] = v;
        else        C16[(long)row * ldc + col] = f2b(v);
      }
    }
  }
}

// ---------------------------------------------------------------------------
// Phase-interleaved NT GEMM (bf16), BK=32 — QK (K=672) and the K-split gates
// GEMM. MODE 3: fp32 atomicAdd epilogue (K-split partial sums).
// ---------------------------------------------------------------------------
template <int BM, int MODE, int OUTF32>
__global__ __launch_bounds__(512, 1) void gemm_p(
    const u16* __restrict__ A, const u16* __restrict__ Bt, void* __restrict__ Cp,
    int M, int N, int K, int lda, int ldb, int ldc,
    long sAhi, long sAlo, long sBhi, long sBlo, long sChi, long sClo,
    const float* __restrict__ aux1, const float* __restrict__ aux2,
    int auxStride, int causal)
{
  constexpr int MFR   = BM / 32;
  constexpr int NPH   = MFR / 2;
  constexpr int SLOT  = (BM + 256) * 32;
  constexpr int ACH   = BM / 128;
  constexpr int LOADS = ACH + 2;
  __shared__ __align__(16) u16 sm[4 * SLOT];

  int gx = gridDim.x;
  int nwg = gx * gridDim.y;
  int flat = blockIdx.y * gx + blockIdx.x;
  int qq = nwg >> 3, r8 = nwg & 7;
  int xcd = flat & 7, seq = flat >> 3;
  int logical = (xcd < r8 ? xcd * (qq + 1) : r8 * (qq + 1) + (xcd - r8) * qq) + seq;
  int bx = logical % gx, by = logical / gx;
  int m0 = by * BM, n0 = bx * 256;
  if (MODE == 1 && n0 > m0 + BM - 1) return;

  int bz = blockIdx.z, bzh = bz >> 2, bzl = bz & 3;
  A  += bzh * sAhi + bzl * sAlo;
  Bt += bzh * sBhi + bzl * sBlo;
  const float* a1 = aux1 ? aux1 + (long)bz * auxStride : nullptr;
  const float* a2 = aux2 ? aux2 + (long)bz * auxStride : nullptr;
  u16*   C16 = (u16*)Cp + bzh * sChi + bzl * sClo;
  float* C32 = (float*)Cp + bzh * sChi + bzl * sClo;

  int t = threadIdx.x, lane = t & 63, w = t >> 6;
  int l15 = lane & 15, quad = lane >> 4;
  int wr = w >> 2, wc = w & 3;

  int srow = t >> 2;
  int swz = (((t & 3) ^ ((t >> 3) & 3)) * 8);
  const u16* pS[LOADS];
  int coff[LOADS];
#pragma unroll
  for (int c = 0; c < ACH; ++c) {
    pS[c] = A + (long)(m0 + c * 128 + srow) * lda + swz;
    coff[c] = c * 4096 + w * 512;
  }
#pragma unroll
  for (int c = 0; c < 2; ++c) {
    pS[ACH + c] = Bt + (long)(n0 + c * 128 + srow) * ldb + swz;
    coff[ACH + c] = BM * 32 + c * 4096 + w * 512;
  }

  int rswz = (quad ^ ((l15 >> 1) & 3)) * 8;
  int aoff = (wr * (BM / 2) + l15) * 32 + rswz;
  int boff = BM * 32 + (wc * 64 + l15) * 32 + rswz;

  f32x4 acc[MFR][4];
#pragma unroll
  for (int i = 0; i < MFR; i++)
#pragma unroll
    for (int j = 0; j < 4; j++) acc[i][j] = (f32x4){0.f, 0.f, 0.f, 0.f};

  int Keff = (MODE == 2 && causal) ? min(K, m0 + BM) : K;
  int T = Keff >> 5;

  auto STAGE1 = [&](int tt, int c) {
    gl2lds16(pS[c] + (tt << 5), sm + (tt & 3) * SLOT + coff[c]);
  };

  int npre = T < 3 ? T : 3;
  for (int tt = 0; tt < npre; ++tt)
#pragma unroll
    for (int c = 0; c < LOADS; ++c) STAGE1(tt, c);
  if (npre >= 3)      vmwait<2 * LOADS>();
  else if (npre == 2) vmwait<LOADS>();
  else                vmwait<0>();
  __builtin_amdgcn_s_barrier();
  __builtin_amdgcn_sched_barrier(0);

  for (int tq = 0; tq < T; ++tq) {
    u16* Sb = sm + (tq & 3) * SLOT;
    const bool stg = (tq + 3 < T);
    bf16x8 bf[4];
#pragma unroll
    for (int p = 0; p < NPH; ++p) {
      bf16x8 a0 = *reinterpret_cast<const bf16x8*>(Sb + aoff + (2 * p) * 512);
      bf16x8 a1v = *reinterpret_cast<const bf16x8*>(Sb + aoff + (2 * p + 1) * 512);
      if (p == 0) {
#pragma unroll
        for (int j = 0; j < 4; ++j)
          bf[j] = *reinterpret_cast<const bf16x8*>(Sb + boff + j * 512);
      }
      if (stg) {
#pragma unroll
        for (int c = p * LOADS / NPH; c < (p + 1) * LOADS / NPH; ++c)
          STAGE1(tq + 3, c);
      }
      __builtin_amdgcn_s_barrier();
      asm volatile("s_waitcnt lgkmcnt(0)" ::: "memory");
      __builtin_amdgcn_sched_barrier(0);
      __builtin_amdgcn_s_setprio(1);
#pragma unroll
      for (int j = 0; j < 4; ++j)
        acc[2 * p][j] = __builtin_amdgcn_mfma_f32_16x16x32_bf16(a0, bf[j], acc[2 * p][j], 0, 0, 0);
#pragma unroll
      for (int j = 0; j < 4; ++j)
        acc[2 * p + 1][j] = __builtin_amdgcn_mfma_f32_16x16x32_bf16(a1v, bf[j], acc[2 * p + 1][j], 0, 0, 0);
      __builtin_amdgcn_s_setprio(0);
      __builtin_amdgcn_sched_barrier(0);
    }
    if (tq + 1 < T) {
      if (tq + 3 < T)      vmwait<2 * LOADS>();
      else if (tq + 2 < T) vmwait<LOADS>();
      else                 vmwait<0>();
      __builtin_amdgcn_s_barrier();
      __builtin_amdgcn_sched_barrier(0);
    }
  }

  const float rs = 0.03857583749f;  // 1/sqrt(672)
#pragma unroll
  for (int i = 0; i < MFR; i++) {
#pragma unroll
    for (int j = 0; j < 4; j++) {
      int col = n0 + wc * 64 + j * 16 + l15;
      if (col >= N) continue;
#pragma unroll
      for (int rr = 0; rr < 4; rr++) {
        int row = m0 + wr * (BM / 2) + i * 16 + quad * 4 + rr;
        if (row >= M) continue;
        float v = acc[i][j][rr];
        if (MODE == 1) v = (col <= row) ? v * rs * __expf(a1[col] - a2[row]) : 0.f;
        else if (MODE == 2) v = v * a1[row];
        if (MODE == 3) { atomicAdd(&C32[(long)row * ldc + col], v); continue; }
        if (OUTF32) C32[(long)row * ldc + col] = v;
        else        C16[(long)row * ldc + col] = f2b(v);
      }
    }
  }
}

// ---------------------------------------------------------------------------
// transpose with row stride: out[c*R + r] = in[r*ldin + c]; F32IN: fp32 source
// ---------------------------------------------------------------------------
template <int F32IN>
__global__ __launch_bounds__(256) void transpose_any(
    const void* __restrict__ in, u16* __restrict__ out, int R, int C, int ldin,
    long inHi, long inLo, long outStride)
{
  __shared__ u16 tile[64][65];
  int bz = blockIdx.z, bzh = bz >> 2, bzl = bz & 3;
  const u16* in16 = (const u16*)in + bzh * inHi + bzl * inLo;
  const float* inf = (const float*)in + bzh * inHi + bzl * inLo;
  out += (long)bz * outStride;
  int r0 = blockIdx.y * 64, c0 = blockIdx.x * 64;
  int t = threadIdx.x;
  for (int idx = t; idx < 64 * 64; idx += 256) {
    int r = idx >> 6, c = idx & 63;
    int rr = r0 + r, cc = c0 + c;
    u16 v = 0;
    if (rr < R && cc < C) {
      long off = (long)rr * ldin + cc;
      v = F32IN ? f2b(inf[off]) : in16[off];
    }
    tile[r][c] = v;
  }
  __syncthreads();
  for (int idx = t; idx < 64 * 64; idx += 256) {
    int r = idx & 63, c = idx >> 6;
    int rr = r0 + r, cc = c0 + c;
    if (rr < R && cc < C) out[(long)cc * R + rr] = tile[r][c];
  }
}

// ---------------------------------------------------------------------------
// x fp32 -> bf16, 8/thread
__global__ __launch_bounds__(256) void convert_x(
    const float* __restrict__ x, u16* __restrict__ o)
{
  long i = ((long)blockIdx.x * 256 + threadIdx.x) * 8;
  if (i >= (long)4096 * EE) return;
  float4 a = *reinterpret_cast<const float4*>(x + i);
  float4 b = *reinterpret_cast<const float4*>(x + i + 4);
  u16 t8[8] = {f2b(a.x), f2b(a.y), f2b(a.z), f2b(a.w),
               f2b(b.x), f2b(b.y), f2b(b.z), f2b(b.w)};
  *reinterpret_cast<uint4*>(o + i) = *reinterpret_cast<uint4*>(t8);
}

// ---------------------------------------------------------------------------
// Wq|Wk|Wv fp32 -> bf16 packed (3 x 10752)
__global__ __launch_bounds__(256) void prep_wqkv(
    const float* __restrict__ Wq, const float* __restrict__ Wk,
    const float* __restrict__ Wv, u16* __restrict__ o)
{
  int i = blockIdx.x * 256 + threadIdx.x;
  if (i >= 3 * 10752) return;
  int m = i / 10752, j = i % 10752;
  const float* W = (m == 0) ? Wq : (m == 1) ? Wk : Wv;
  o[i] = f2b(W[j]);
}

// ---------------------------------------------------------------------------
// Wg3 (256 x 2688 bf16): rows r<24: r=seg*8+j -> (j<4?W_ig:W_fg)[seg*H+c, j&3]
// rows 24..255 zero (B-staging pad for the gates GEMM).
__global__ __launch_bounds__(256) void prep_wg3(
    const float* __restrict__ Wig, const float* __restrict__ Wfg,
    u16* __restrict__ o)
{
  int i = blockIdx.x * 256 + threadIdx.x;
  if (i >= 256 * HH) return;
  int r = i / HH, c = i % HH;
  float v = 0.f;
  if (r < 24) {
    int seg = r >> 3, j = r & 7;
    const float* W = (j < 4) ? Wig : Wfg;
    v = W[(long)(seg * HH + c) * 4 + (j & 3)];
  }
  o[i] = f2b(v);
}

// ---------------------------------------------------------------------------
// FUSED: depthwise causal conv (KS=4) + bias + silu + headwise 4x4 q/k/v.
// One thread per (bs, nph). Tap w=3 IS x_m -> reused for the v-projection.
// (r5 form — measured fast; r6's block-per-(b,s) gate fusion regressed.)
// ---------------------------------------------------------------------------
__global__ __launch_bounds__(256) void conv_head(
    const u16* __restrict__ xinner, const float* __restrict__ cw,
    const float* __restrict__ cb, const u16* __restrict__ Wqkv,
    u16* __restrict__ xca, u16* __restrict__ q, u16* __restrict__ k,
    u16* __restrict__ v)
{
  long idx = (long)blockIdx.x * 256 + threadIdx.x;
  if (idx >= (long)BB * SS * NPHH) return;
  int nph = (int)(idx % NPHH);
  long bs = idx / NPHH;
  int s = (int)(bs % SS);
  int h4 = nph * 4;
  float4 acc = *reinterpret_cast<const float4*>(cb + h4);
  uint2 xmr = {0, 0};  // tap w=3 = x_m row bs (always in-bounds)
#pragma unroll
  for (int w = 0; w < 4; w++) {
    int sp = s + w - 3;
    if (sp < 0) continue;
    uint2 xr = *reinterpret_cast<const uint2*>(xinner + (bs + w - 3) * H2 + h4);
    if (w == 3) xmr = xr;
    const u16* xh = (const u16*)&xr;
    float4 cwv = *reinterpret_cast<const float4*>(cw + w * HH + h4);
    acc.x += b2f(xh[0]) * cwv.x;
    acc.y += b2f(xh[1]) * cwv.y;
    acc.z += b2f(xh[2]) * cwv.z;
    acc.w += b2f(xh[3]) * cwv.w;
  }
  float xaf[4] = {silu_f(acc.x), silu_f(acc.y), silu_f(acc.z), silu_f(acc.w)};
  u16 xa16[4] = {f2b(xaf[0]), f2b(xaf[1]), f2b(xaf[2]), f2b(xaf[3])};
#pragma unroll
  for (int d = 0; d < 4; d++) xaf[d] = b2f(xa16[d]);
  const u16* xm = (const u16*)&xmr;
  float xmf[4];
#pragma unroll
  for (int d = 0; d < 4; d++) xmf[d] = b2f(xm[d]);
  *reinterpret_cast<uint2*>(xca + bs * HH + h4) = *reinterpret_cast<uint2*>(xa16);

  union { uint4 v4[2]; u16 h[16]; } wq, wk, wv;
  const uint4* wqp = reinterpret_cast<const uint4*>(Wqkv + nph * 16);
  const uint4* wkp = reinterpret_cast<const uint4*>(Wqkv + 10752 + nph * 16);
  const uint4* wvp = reinterpret_cast<const uint4*>(Wqkv + 21504 + nph * 16);
  wq.v4[0] = wqp[0]; wq.v4[1] = wqp[1];
  wk.v4[0] = wkp[0]; wk.v4[1] = wkp[1];
  wv.v4[0] = wvp[0]; wv.v4[1] = wvp[1];
  u16 qo[4], ko[4], vo[4];
#pragma unroll
  for (int o = 0; o < 4; o++) {
    float aq = 0.f, ak = 0.f, av = 0.f;
#pragma unroll
    for (int d = 0; d < 4; d++) {
      aq += xaf[d] * b2f(wq.h[d * 4 + o]);
      ak += xaf[d] * b2f(wk.h[d * 4 + o]);
      av += xmf[d] * b2f(wv.h[d * 4 + o]);
    }
    qo[o] = f2b(aq); ko[o] = f2b(ak); vo[o] = f2b(av);
  }
  long ob = bs * HH + h4;
  *reinterpret_cast<uint2*>(q + ob) = *reinterpret_cast<uint2*>(qo);
  *reinterpret_cast<uint2*>(k + ob) = *reinterpret_cast<uint2*>(ko);
  *reinterpret_cast<uint2*>(v + ob) = *reinterpret_cast<uint2*>(vo);
}

// ---------------------------------------------------------------------------
// scan: per (b,n): ip/fp from G (12288x24) + bias; cs = cumsum(logsig(fp));
// a = ip - cs; rmax = prefix-max(a); m = cs + rmax.
// 256 threads x 8 serial elems; wave shfl_up scans + 4-wave LDS combine.
// ---------------------------------------------------------------------------
__global__ __launch_bounds__(256) void scan_kernel(
    const float* __restrict__ G, const float* __restrict__ big,
    const float* __restrict__ bfg,
    float* __restrict__ avec, float* __restrict__ rmaxvec, float* __restrict__ mvec)
{
  __shared__ float wsum[4], wmax[4];
  int bn = blockIdx.x;
  int b = bn >> 2, n = bn & 3;
  int t = threadIdx.x, lane = t & 63, wv = t >> 6;
  float bi = big[n], bf = bfg[n];
  int i0 = t * 8;
  float ip[8], ls[8];
  float run = 0.f;
#pragma unroll
  for (int kk = 0; kk < 8; ++kk) {
    long tk = (long)b * SS + i0 + kk;
    ip[kk] = G[tk * 24 + n] + G[(4096 + tk) * 24 + 8 + n] +
             G[(8192 + tk) * 24 + 16 + n] + bi;
    float fp = G[tk * 24 + 4 + n] + G[(4096 + tk) * 24 + 12 + n] +
               G[(8192 + tk) * 24 + 20 + n] + bf;
    run += logsig_f(fp);
    ls[kk] = run;
  }
  // inclusive sum-scan of per-thread totals across the wave
  float v = run;
#pragma unroll
  for (int off = 1; off < 64; off <<= 1) {
    float o = __shfl_up(v, off);
    if (lane >= off) v += o;
  }
  if (lane == 63) wsum[wv] = v;
  __syncthreads();
  float woff = 0.f;
  for (int u = 0; u < wv; ++u) woff += wsum[u];
  float excl = v - run + woff;   // exclusive prefix for this thread's chunk
  float a[8], lm[8];
  float runm = -3.4e38f;
#pragma unroll
  for (int kk = 0; kk < 8; ++kk) {
    float cs = excl + ls[kk];
    ls[kk] = cs;
    a[kk] = ip[kk] - cs;
    runm = fmaxf(runm, a[kk]);
    lm[kk] = runm;
    avec[(long)bn * SS + i0 + kk] = a[kk];
  }
  // inclusive max-scan of per-thread maxima across the wave
  float mv = runm;
#pragma unroll
  for (int off = 1; off < 64; off <<= 1) {
    float o = __shfl_up(mv, off);
    if (lane >= off) mv = fmaxf(mv, o);
  }
  if (lane == 63) wmax[wv] = mv;
  __syncthreads();
  float woffm = -3.4e38f;
  for (int u = 0; u < wv; ++u) woffm = fmaxf(woffm, wmax[u]);
  float pm = __shfl_up(mv, 1);
  float pre = (lane == 0) ? woffm : fmaxf(woffm, pm);
#pragma unroll
  for (int kk = 0; kk < 8; ++kk) {
    float r = fmaxf(pre, lm[kk]);
    rmaxvec[(long)bn * SS + i0 + kk] = r;
    mvec[(long)bn * SS + i0 + kk] = ls[kk] + r;
  }
}

// ---------------------------------------------------------------------------
// causal row sums of P -> inv_n (vectorized uint4 + in-bounds scalar tail)
__global__ __launch_bounds__(256) void rowsum_kernel(
    const u16* __restrict__ P, const float* __restrict__ mvec, float* __restrict__ invn,
    long Pstride)
{
  int bz = blockIdx.z;
  P += (long)bz * Pstride;
  mvec += (long)bz * SS;
  invn += (long)bz * SS;
  int row = (blockIdx.x * 256 + threadIdx.x) >> 6;
  int lane = threadIdx.x & 63;
  if (row >= SS) return;
  const u16* pr = P + (long)row * SS;
  float s = 0.f;
  int j0 = lane * 8;
  for (; j0 + 7 <= row; j0 += 512) {
    uint4 u = *reinterpret_cast<const uint4*>(pr + j0);
    const u16* e = (const u16*)&u;
#pragma unroll
    for (int q = 0; q < 8; ++q) s += b2f(e[q]);
  }
  if (j0 <= row) {
    for (int q = 0; j0 + q <= row; ++q) s += b2f(pr[j0 + q]);
  }
#pragma unroll
  for (int off = 32; off > 0; off >>= 1) s += __shfl_down(s, off);
  if (lane == 0) {
    float n = fmaxf(fabsf(s), __expf(-mvec[row]));
    invn[row] = 1.f / (n + 1e-6f);
  }
}

// ---------------------------------------------------------------------------
// multi-head layernorm + skip + gate (paired u32 bf16 loads)
__global__ __launch_bounds__(256) void ln_skip_gate(
    const u16* __restrict__ h, const u16* __restrict__ xca,
    const u16* __restrict__ xinner, const float* __restrict__ normw,
    const float* __restrict__ skipw, u16* __restrict__ hs)
{
  int row = (blockIdx.x * 256 + threadIdx.x) >> 6;  // (b*NH+n)*S + s
  int lane = threadIdx.x & 63;
  if (row >= BB * NHH * SS) return;
  int s = row % SS;
  int n = (row / SS) % NHH;
  int b = row / (SS * NHH);
  const u16* hr = h + (long)row * DHH;
  float sum = 0.f, ss = 0.f;
  float vx[6], vy[6];
#pragma unroll
  for (int i = 0; i < 6; ++i) {
    int d2 = lane + i * 64;
    float x = 0.f, y = 0.f;
    if (d2 < DHH / 2) {
      u32 u = *reinterpret_cast<const u32*>(hr + d2 * 2);
      x = b2f((u16)u); y = b2f((u16)(u >> 16));
    }
    vx[i] = x; vy[i] = y;
    sum += x + y; ss += x * x + y * y;
  }
#pragma unroll
  for (int off = 32; off > 0; off >>= 1) { sum += __shfl_down(sum, off); ss += __shfl_down(ss, off); }
  sum = __shfl(sum, 0); ss = __shfl(ss, 0);
  float mu = sum / (float)DHH;
  float var = ss / (float)DHH - mu * mu;
  float rstd = rsqrtf(var + 1e-5f);
  long bs = (long)b * SS + s;
#pragma unroll
  for (int i = 0; i < 6; ++i) {
    int d2 = lane + i * 64;
    if (d2 >= DHH / 2) continue;
    int c = n * DHH + d2 * 2;
    float2 nw = *reinterpret_cast<const float2*>(normw + c);
    float2 sw = *reinterpret_cast<const float2*>(skipw + c);
    u32 xcu = *reinterpret_cast<const u32*>(xca + bs * HH + c);
    u32 zu  = *reinterpret_cast<const u32*>(xinner + bs * H2 + HH + c);
    float h0 = (vx[i] - mu) * rstd * nw.x + sw.x * b2f((u16)xcu);
    float h1 = (vy[i] - mu) * rstd * nw.y + sw.y * b2f((u16)(xcu >> 16));
    float o0 = h0 * silu_f(b2f((u16)zu));
    float o1 = h1 * silu_f(b2f((u16)(zu >> 16)));
    u32 ou = (u32)f2b(o0) | ((u32)f2b(o1) << 16);
    *reinterpret_cast<u32*>(hs + bs * HH + c) = ou;
  }
}

// ---------------------------------------------------------------------------
__global__ __launch_bounds__(256) void fill_sentinel(float* out, float v, long n) {
  long i = (long)blockIdx.x * 256 + threadIdx.x;
  if (i < n) out[i] = v;
}

// ---------------------------------------------------------------------------
extern "C" void kernel_launch(void* const* d_in, const int* in_sizes, int n_in,
                              void* d_out, int out_size, void* d_ws, size_t ws_size,
                              hipStream_t stream)
{
  const float* x      = (const float*)d_in[0];
  const float* W_in   = (const float*)d_in[1];
  const float* conv_w = (const float*)d_in[2];
  const float* conv_b = (const float*)d_in[3];
  const float* Wq     = (const float*)d_in[4];
  const float* Wk     = (const float*)d_in[5];
  const float* Wv     = (const float*)d_in[6];
  const float* W_ig   = (const float*)d_in[7];
  const float* b_ig   = (const float*)d_in[8];
  const float* W_fg   = (const float*)d_in[9];
  const float* b_fg   = (const float*)d_in[10];
  const float* norm_w = (const float*)d_in[11];
  const float* skipw  = (const float*)d_in[12];
  const float* W_out  = (const float*)d_in[13];
  float* out = (float*)d_out;
  const long SD = (long)SS * DHH;     // head slice elems
  const long SP = (long)SS * SS;
  const long BH = (long)SS * HH;      // per-batch elems of (S,H)

  u16* ws = (u16*)d_ws;
  size_t off = 0;
  auto alloc = [&](size_t n) { u16* p = ws + off; off += n; return p; };
  u16* x_inner = alloc((size_t)4096 * H2);
  u16* xca     = alloc((size_t)4096 * HH);
  u16* qb      = alloc((size_t)4096 * HH);   // W_inT -> q -> hs
  u16* kb      = alloc((size_t)4096 * HH);   // xbf -> k -> h
  u16* vb      = alloc((size_t)4096 * HH);   // v -> W_outT
  float* fvec  = (float*)(ws + off);
  off += 4 * 16384 * 2;
  float* avec    = fvec;
  float* rmaxvec = avec + 16384;
  float* mvec    = rmaxvec + 16384;
  float* invn    = mvec + 16384;
  u16* vt8 = alloc((size_t)8 * SD);
  u16* Pb8 = alloc((size_t)8 * SP);
  size_t need = off * 2;
  long outn = (long)4096 * EE;

  if (ws_size < need) {
    fill_sentinel<<<dim3((outn + 255) / 256), 256, 0, stream>>>(
        out, 200.f + 0.01f * (float)(ws_size >> 20), outn);
    return;
  }

  // overlays
  u16* W_inT  = qb;                       // consumed before conv_head writes q
  u16* xbf    = kb;                       // consumed before conv_head writes k
  u16* W_outT = vb;                       // written after v's last use
  u16* hbuf   = kb;                       // h (bn,S,DH) after k's last use
  u16* hsbuf  = qb;                       // hs after q's last use
  float* G    = (float*)(Pb8 + 344064);   // 12288x24 fp32, consumed before QK
  u16* Wqkv   = Pb8 + 933888;             // 3x10752, consumed before QK
  u16* Wg3    = Pb8 + 966144;             // 256x2688 bf16 gate B, before QK

  prep_wqkv<<<dim3(126, 1, 1), 256, 0, stream>>>(Wq, Wk, Wv, Wqkv);
  prep_wg3<<<dim3(2688, 1, 1), 256, 0, stream>>>(W_ig, W_fg, Wg3);
  fill_sentinel<<<dim3(1152, 1, 1), 256, 0, stream>>>(G, 0.f, 294912);
  transpose_any<1><<<dim3(84, 32, 1), 256, 0, stream>>>(
      W_in, W_inT, EE, H2, H2, 0, 0, 0);
  convert_x<<<dim3(4096, 1, 1), 256, 0, stream>>>(x, xbf);
  // x_inner = x @ W_in : M=4096 N=5376 K=2048 (128x256 tiles, 672 blocks)
  gemm8<0, 0><<<dim3(21, 32, 1), 512, 0, stream>>>(
      xbf, W_inT, x_inner, 4096, H2, EE, EE, EE, H2,
      0, 0, 0, 0, 0, 0, nullptr, nullptr, 0, 0);
  // fused conv+silu+headwise: writes xca, q, k, v (r5 fast form)
  conv_head<<<dim3(10752, 1, 1), 256, 0, stream>>>(
      x_inner, conv_w, conv_b, Wqkv, xca, qb, kb, vb);
  // gates: [q;k;v] (12288 x 2688) @ Wg3^T -> G (12288 x 24), K split 4x672
  // via bz (bzl*sAlo = flat column offset); MODE 3 = fp32 atomicAdd epilogue
  gemm_p<128, 3, 1><<<dim3(1, 96, 4), 512, 0, stream>>>(
      qb, Wg3, G, 12288, 24, DHH, HH, HH, 24,
      0, DHH, 0, DHH, 0, 0, nullptr, nullptr, 0, 0);
  scan_kernel<<<dim3(8, 1, 1), 256, 0, stream>>>(G, b_ig, b_fg, avec, rmaxvec, mvec);
  // v^T per (b,n): (DH, S)
  transpose_any<0><<<dim3(11, 32, 8), 256, 0, stream>>>(
      vb, vt8, SS, DHH, HH, BH, DHH, SD);
  // P = (q k^T / sqrt(DH)) * exp(a[col]-rmax[row]), causal; K=672 -> BK32 path
  gemm_p<256, 1, 0><<<dim3(8, 8, 8), 512, 0, stream>>>(
      qb, kb, Pb8, SS, SS, DHH, HH, HH, SS,
      BH, DHH, BH, DHH, 4 * SP, SP, avec, rmaxvec, SS, 0);
  rowsum_kernel<<<dim3(512, 1, 8), 256, 0, stream>>>(Pb8, mvec, invn, SP);
  // h = (P @ v) * inv_n, into (bn, S, DH); Keff = m0+128 (mult of 64 ok);
  // B over-reads vt8 rows 672..767 (in-bounds garbage, masked by col<N)
  gemm8<2, 0><<<dim3(3, 16, 8), 512, 0, stream>>>(
      Pb8, vt8, hbuf, SS, DHH, SS, SS, SS, DHH,
      4 * SP, SP, 4 * SD, SD, 4 * SD, SD, invn, nullptr, SS, 1);
  transpose_any<1><<<dim3(32, 42, 1), 256, 0, stream>>>(
      W_out, W_outT, HH, EE, EE, 0, 0, 0);
  ln_skip_gate<<<dim3(4096, 1, 1), 256, 0, stream>>>(
      hbuf, xca, x_inner, norm_w, skipw, hsbuf);
  gemm8<0, 1><<<dim3(8, 32, 1), 512, 0, stream>>>(
      hsbuf, W_outT, out, 4096, EE, HH, HH, HH, EE,
      0, 0, 0, 0, 0, 0, nullptr, nullptr, 0, 0);
}